// Round 1
// baseline (6583.346 us; speedup 1.0000x reference)
//
#include <hip/hip_runtime.h>
#include <hip/hip_bf16.h>
#include <cstdint>
#include <cstddef>

#define B_   32
#define T_   64
#define S_   128
#define EH   512
#define DH   512
#define ATT  256
#define EMBD 256
#define V_   32000
#define VO   31999
#define G3   1536

#define ATTN_OFF 65533952   /* 32*64*31999 */

typedef __attribute__((ext_vector_type(8))) short bf16x8;
typedef __attribute__((ext_vector_type(4))) float f32x4;

static __device__ __forceinline__ unsigned short f2bf(float f) {
    union { float f; unsigned u; } x; x.f = f;
    unsigned r = (x.u + 0x7fffu + ((x.u >> 16) & 1u)) >> 16;
    return (unsigned short)r;
}

static __device__ __forceinline__ float fast_tanh(float x) {
    float xc = fminf(fmaxf(x, -15.0f), 15.0f);
    float e = __expf(2.0f * xc);
    return (e - 1.0f) / (e + 1.0f);
}

static __device__ __forceinline__ float fast_sig(float x) {
    return 1.0f / (1.0f + __expf(-x));
}

// ---------------------------------------------------------------------------
// Prep: transpose (512,256) -> (256,512) fp32   (used for W_enc and W_dec)
__global__ void k_trans_512x256(const float* __restrict__ in, float* __restrict__ out) {
    __shared__ float tile[32][33];
    int c0 = blockIdx.x * 32;
    int r0 = blockIdx.y * 32;
    int tx = threadIdx.x, ty = threadIdx.y;
#pragma unroll
    for (int q = 0; q < 4; q++)
        tile[ty + q*8][tx] = in[(r0 + ty + q*8) * 256 + c0 + tx];
    __syncthreads();
#pragma unroll
    for (int q = 0; q < 4; q++)
        out[(c0 + ty + q*8) * 512 + r0 + tx] = tile[tx][ty + q*8];
}

// ---------------------------------------------------------------------------
// Prep: W_fc (512 x 31999) fp32 -> W_fcT (32000 x 512) bf16, pad row zeroed
__global__ void k_wfc(const float* __restrict__ wfc, unsigned short* __restrict__ outT) {
    __shared__ float tile[32][33];
    int n0 = blockIdx.x * 32;
    int k0 = blockIdx.y * 32;
    int tx = threadIdx.x, ty = threadIdx.y;
#pragma unroll
    for (int q = 0; q < 4; q++) {
        int k = k0 + ty + q*8;
        int n = n0 + tx;
        tile[ty + q*8][tx] = (n < VO) ? wfc[(size_t)k * VO + n] : 0.0f;
    }
    __syncthreads();
#pragma unroll
    for (int q = 0; q < 4; q++) {
        int n = n0 + ty + q*8;
        int k = k0 + tx;
        outT[(size_t)n * 512 + k] = f2bf(tile[tx][ty + q*8]);
    }
}

// ---------------------------------------------------------------------------
// Prep: pack GRU weights into MFMA B-fragment order, bf16.
// idx = (((j*32 + kc)*4 + q)*64 + lane)*8 + e
__global__ void k_wpack(const float* __restrict__ W_ih, const float* __restrict__ W_hh,
                        unsigned short* __restrict__ Wp) {
    int idx = blockIdx.x * 256 + threadIdx.x;
    int e    = idx & 7;
    int lane = (idx >> 3) & 63;
    int q    = (idx >> 9) & 3;
    int kc   = (idx >> 11) & 31;
    int j    = idx >> 16;
    int io = lane & 15, ko = lane >> 4;
    int i = j * 16 + io;
    int k = kc * 32 + ko * 8 + e;
    int n = (q == 0) ? i : (q == 1) ? (512 + i) : (1024 + i);
    float val;
    if (k < 512) {
        val = (q == 3) ? 0.0f : W_ih[(size_t)n * 768 + 256 + k];
    } else {
        val = (q == 2) ? 0.0f : W_hh[(size_t)n * 512 + (k - 512)];
    }
    Wp[idx] = f2bf(val);
}

// ---------------------------------------------------------------------------
// Prep: enc_proj (4096 x 256) = encoder_outputs (4096 x 512) @ W_enc
__global__ __launch_bounds__(256) void k_encproj(const float* __restrict__ enc,
                                                 const float* __restrict__ WencT,
                                                 float* __restrict__ ep) {
    int row0 = blockIdx.x * 16;
    int n = threadIdx.x;
    const float* wr = WencT + (size_t)n * 512;
    float acc[16];
#pragma unroll
    for (int r = 0; r < 16; r++) acc[r] = 0.0f;
    for (int k = 0; k < 512; k += 4) {
        float4 w = *(const float4*)(wr + k);
#pragma unroll
        for (int r = 0; r < 16; r++) {
            float4 x = *(const float4*)(enc + (size_t)(row0 + r) * 512 + k);
            acc[r] += x.x * w.x + x.y * w.y + x.z * w.z + x.w * w.w;
        }
    }
#pragma unroll
    for (int r = 0; r < 16; r++)
        ep[(size_t)(row0 + r) * 256 + n] = acc[r];
}

// ---------------------------------------------------------------------------
// Prep: gx_emb (2048 x 1536) = embedding[y] @ W_ih[:, :256]^T + b_ih
__global__ __launch_bounds__(256) void k_gxemb(const int* __restrict__ y,
                                               const float* __restrict__ embt,
                                               const float* __restrict__ W_ih,
                                               const float* __restrict__ bih,
                                               float* __restrict__ gx) {
    int row0 = blockIdx.y * 16;
    int col = blockIdx.x * 256 + threadIdx.x;
    const float* wr = W_ih + (size_t)col * 768;
    float acc[16];
#pragma unroll
    for (int r = 0; r < 16; r++) acc[r] = 0.0f;
    for (int k = 0; k < 256; k += 4) {
        float4 w = *(const float4*)(wr + k);
#pragma unroll
        for (int r = 0; r < 16; r++) {
            const float* xr = embt + (size_t)y[row0 + r] * 256 + k;  // uniform
            float4 x = *(const float4*)xr;
            acc[r] += x.x * w.x + x.y * w.y + x.z * w.z + x.w * w.w;
        }
    }
    float bv = bih[col];
#pragma unroll
    for (int r = 0; r < 16; r++)
        gx[(size_t)(row0 + r) * G3 + col] = acc[r] + bv;
}

// ---------------------------------------------------------------------------
// Recurrence: one block per batch, NO cross-block communication, no grid sync.
// 512 threads = 8 waves. Per step:
//   dec GEMV (fp32) -> energy/tanh -> softmax -> context GEMV (fp32) ->
//   GRU via MFMA with broadcast-A (single X row replicated across io lanes) ->
//   lane-local gating.
// GRU weights streamed from the packed Wp layout; zero half-fragments of the
// n-gate (q2 k>=512 / q3 k<512) are skipped, so 3 MB read per block per step.
__global__ __launch_bounds__(512) void k_recur(
        const float* __restrict__ WdecT, const float* __restrict__ ep,
        const float* __restrict__ v, const int* __restrict__ mask,
        const float* __restrict__ enc, float* __restrict__ attn_out,
        const unsigned short* __restrict__ Wp, const float* __restrict__ gx_emb,
        const float* __restrict__ b_hh, const float* __restrict__ dinit,
        unsigned short* __restrict__ Hall) {
    __shared__ float hbuf[512];                       // h (fp32)
    __shared__ __align__(16) unsigned short Xs[1024]; // [ctx(512) | h(512)] bf16
    __shared__ float decp[512];
    __shared__ float es[128];
    __shared__ float red[2];
    __shared__ float vs[256];
    __shared__ float bhs[1536];
    __shared__ float ges[1536];
    __shared__ int   msk[128];

    int b = blockIdx.x, tid = threadIdx.x;
    int w = tid >> 6, lane = tid & 63;
    int io = lane & 15, ko = lane >> 4;

    // one-time init: h, X h-half, constants
    {
        float hv = dinit[b * 512 + tid];
        hbuf[tid] = hv;
        Xs[512 + tid] = f2bf(hv);
        bhs[tid]        = b_hh[tid];
        bhs[512 + tid]  = b_hh[512 + tid];
        bhs[1024 + tid] = b_hh[1024 + tid];
        if (tid < 256) vs[tid] = v[tid];
        if (tid < 128) msk[tid] = mask[b * 128 + tid];
    }
    __syncthreads();

    const float* epb  = ep  + (size_t)b * 128 * 256;
    const float* encb = enc + (size_t)b * 128 * 512;

    for (int t = 0; t < T_; t++) {
        // prefetch this step's gx_emb row into LDS (consumed in gating)
        {
            const float* ge = gx_emb + (size_t)(b * 64 + t) * G3;
            ges[tid]        = ge[tid];
            ges[512 + tid]  = ge[512 + tid];
            ges[1024 + tid] = ge[1024 + tid];
        }
        // ---- dec = h @ W_dec (fp32), K split across thread halves ----
        {
            int d = tid & 255, half = tid >> 8;
            const float* wr = WdecT + (size_t)d * 512 + half * 256;
            const float* hb = hbuf + half * 256;
            float acc = 0.0f;
#pragma unroll 8
            for (int k = 0; k < 256; k += 4) {
                float4 wv = *(const float4*)(wr + k);
                float4 xv = *(const float4*)(hb + k);
                acc += xv.x * wv.x + xv.y * wv.y + xv.z * wv.z + xv.w * wv.w;
            }
            decp[tid] = acc;
        }
        __syncthreads();
        if (tid < 256) decp[tid] += decp[tid + 256];
        __syncthreads();
        // ---- energy: wave w handles s = w*16 .. w*16+15 ----
        {
            float d0 = decp[lane], d1 = decp[lane + 64],
                  d2 = decp[lane + 128], d3 = decp[lane + 192];
            float v0 = vs[lane], v1 = vs[lane + 64],
                  v2 = vs[lane + 128], v3 = vs[lane + 192];
#pragma unroll
            for (int si = 0; si < 16; si++) {
                int s = w * 16 + si;
                const float* er = epb + (size_t)s * 256;
                float e = fast_tanh(er[lane] + d0) * v0
                        + fast_tanh(er[lane + 64] + d1) * v1
                        + fast_tanh(er[lane + 128] + d2) * v2
                        + fast_tanh(er[lane + 192] + d3) * v3;
#pragma unroll
                for (int o = 32; o; o >>= 1) e += __shfl_xor(e, o);
                if (lane == 0)
                    es[s] = (msk[s] == 0) ? -1e9f : e;
            }
        }
        __syncthreads();
        // ---- softmax over 128 ----
        if (tid < 64) {
            float a = fmaxf(es[tid], es[tid + 64]);
#pragma unroll
            for (int o = 32; o; o >>= 1) a = fmaxf(a, __shfl_xor(a, o));
            if (tid == 0) red[0] = a;
        }
        __syncthreads();
        float mx = red[0];
        if (tid < 128) es[tid] = __expf(es[tid] - mx);
        __syncthreads();
        if (tid < 64) {
            float a = es[tid] + es[tid + 64];
#pragma unroll
            for (int o = 32; o; o >>= 1) a += __shfl_xor(a, o);
            if (tid == 0) red[1] = a;
        }
        __syncthreads();
        float inv = 1.0f / red[1];
        if (tid < 128) {
            float aw = es[tid] * inv;
            es[tid] = aw;
            attn_out[(size_t)b * (T_ * S_) + t * S_ + tid] = aw;
        }
        __syncthreads();
        // ---- context: thread d = tid over 512 dims (fp32) ----
        {
            float a1 = 0.0f;
            const float* eb = encb + tid;
#pragma unroll 8
            for (int s = 0; s < 128; s++)
                a1 += es[s] * eb[(size_t)s * 512];
            Xs[tid] = f2bf(a1);
        }
        __syncthreads();
        // ---- GRU MFMA: wave w handles j = w*4 .. w*4+3 ----
        // A-fragment: broadcast (all io lanes read same LDS addr) => every
        // C row equals x @ W, so any (ko,reg) gives the result; we use
        // ko==0 / reg 0.
        float rj[4], zj[4], xj[4], hj[4];
        {
            const char* xb = (const char*)Xs + ko * 16;
#pragma unroll 1
            for (int jj = 0; jj < 4; jj++) {
                int j = w * 4 + jj;
                const uint4* bb = (const uint4*)Wp + ((size_t)j << 13) + lane;
                f32x4 aR = {0.f, 0.f, 0.f, 0.f};
                f32x4 aZ = aR, aNX = aR, aNH = aR;
#pragma unroll
                for (int kc = 0; kc < 32; kc++) {
                    bf16x8 a = *(const bf16x8*)(xb + kc * 64);
                    uint4 b0 = bb[(kc * 4 + 0) * 64];
                    uint4 b1 = bb[(kc * 4 + 1) * 64];
                    aR = __builtin_amdgcn_mfma_f32_16x16x32_bf16(a, *(const bf16x8*)&b0, aR, 0, 0, 0);
                    aZ = __builtin_amdgcn_mfma_f32_16x16x32_bf16(a, *(const bf16x8*)&b1, aZ, 0, 0, 0);
                    if (kc < 16) {
                        uint4 b2 = bb[(kc * 4 + 2) * 64];
                        aNX = __builtin_amdgcn_mfma_f32_16x16x32_bf16(a, *(const bf16x8*)&b2, aNX, 0, 0, 0);
                    } else {
                        uint4 b3 = bb[(kc * 4 + 3) * 64];
                        aNH = __builtin_amdgcn_mfma_f32_16x16x32_bf16(a, *(const bf16x8*)&b3, aNH, 0, 0, 0);
                    }
                }
                rj[jj] = aR[0]; zj[jj] = aZ[0]; xj[jj] = aNX[0]; hj[jj] = aNH[0];
            }
        }
        __syncthreads();   // all waves done reading Xs
        // ---- gating: lanes ko==0, i = j*16 + io ----
        if (ko == 0) {
            int m = b * 64 + t;
#pragma unroll
            for (int jj = 0; jj < 4; jj++) {
                int i = (w * 4 + jj) * 16 + io;
                float r = fast_sig(ges[i] + rj[jj] + bhs[i]);
                float z = fast_sig(ges[512 + i] + zj[jj] + bhs[512 + i]);
                float n = fast_tanh(ges[1024 + i] + xj[jj] + r * (hj[jj] + bhs[1024 + i]));
                float prev = hbuf[i];
                float hv = (1.0f - z) * n + z * prev;
                hbuf[i] = hv;
                Xs[512 + i] = f2bf(hv);
                Hall[(size_t)m * 512 + i] = f2bf(hv);
            }
        }
        __syncthreads();
    }
}

// ---------------------------------------------------------------------------
// FC: out (2048 x 31999) = H_all (2048x512) bf16 @ W_fcT^T bf16 + b_fc
// 128x128 tiles, BK=32. Epilogue stages C in LDS and writes contiguous rows.
__global__ __launch_bounds__(256) void k_fc(const unsigned short* __restrict__ A,
                                            const unsigned short* __restrict__ Bt,
                                            const float* __restrict__ bias,
                                            float* __restrict__ out) {
    __shared__ char smem[65536];
    unsigned short* Abuf = (unsigned short*)smem;            // 128*40 = 10240 B
    unsigned short* Bbuf = (unsigned short*)(smem + 10240);  // 10240 B
    int tid = threadIdx.x;
    int n0 = blockIdx.x * 128, m0 = blockIdx.y * 128;
    int w = tid >> 6, lane = tid & 63;
    int wm = w >> 1, wn = w & 1;
    int io = lane & 15, ko = lane >> 4;

    const uint4* Ag = (const uint4*)A;
    const uint4* Bg = (const uint4*)Bt;

    f32x4 z4 = {0.f, 0.f, 0.f, 0.f};
    f32x4 acc[4][4];
#pragma unroll
    for (int a = 0; a < 4; a++)
#pragma unroll
        for (int b = 0; b < 4; b++) acc[a][b] = z4;

    for (int k0 = 0; k0 < 512; k0 += 32) {
        uint4 av[2], bv[2];
#pragma unroll
        for (int u = 0; u < 2; u++) {
            int c = tid + u * 256;
            int r = c >> 2, ch = c & 3;
            av[u] = Ag[(size_t)(m0 + r) * 64 + (k0 >> 3) + ch];
            bv[u] = Bg[(size_t)(n0 + r) * 64 + (k0 >> 3) + ch];
        }
        __syncthreads();
#pragma unroll
        for (int u = 0; u < 2; u++) {
            int c = tid + u * 256;
            int r = c >> 2, ch = c & 3;
            *(uint4*)((char*)Abuf + r * 80 + ch * 16) = av[u];
            *(uint4*)((char*)Bbuf + r * 80 + ch * 16) = bv[u];
        }
        __syncthreads();
        bf16x8 af[4], bf[4];
#pragma unroll
        for (int s = 0; s < 4; s++) {
            af[s] = *(const bf16x8*)((char*)Abuf + (wm * 64 + s * 16 + io) * 80 + ko * 16);
            bf[s] = *(const bf16x8*)((char*)Bbuf + (wn * 64 + s * 16 + io) * 80 + ko * 16);
        }
#pragma unroll
        for (int sm = 0; sm < 4; sm++)
#pragma unroll
            for (int sn = 0; sn < 4; sn++)
                acc[sm][sn] = __builtin_amdgcn_mfma_f32_16x16x32_bf16(af[sm], bf[sn], acc[sm][sn], 0, 0, 0);
    }

    __syncthreads();
    float* Cst = (float*)smem;   // 128 x 128 fp32 = 64 KB
#pragma unroll
    for (int sm = 0; sm < 4; sm++)
#pragma unroll
        for (int sn = 0; sn < 4; sn++) {
            int cc = wn * 64 + sn * 16 + io;
#pragma unroll
            for (int reg = 0; reg < 4; reg++) {
                int rr = wm * 64 + sm * 16 + ko * 4 + reg;
                Cst[rr * 128 + cc] = acc[sm][sn][reg];
            }
        }
    __syncthreads();
    {
        int c = tid & 127, rh = tid >> 7;
        int ng = n0 + c;
        if (ng < VO) {
            float bv = bias[ng];
#pragma unroll 8
            for (int i = 0; i < 64; i++) {
                int r = i * 2 + rh;
                out[(size_t)(m0 + r) * VO + ng] = Cst[r * 128 + c] + bv;
            }
        }
    }
}

// ---------------------------------------------------------------------------
extern "C" void kernel_launch(void* const* d_in, const int* in_sizes, int n_in,
                              void* d_out, int out_size, void* d_ws, size_t ws_size,
                              hipStream_t stream) {
    const int*   y      = (const int*)d_in[0];
    const float* enc    = (const float*)d_in[1];
    const float* dinit  = (const float*)d_in[2];
    const int*   mask   = (const int*)d_in[3];
    const float* embt   = (const float*)d_in[4];
    const float* W_enc  = (const float*)d_in[5];
    const float* W_dec  = (const float*)d_in[6];
    const float* v      = (const float*)d_in[7];
    const float* W_ih   = (const float*)d_in[8];
    const float* W_hh   = (const float*)d_in[9];
    const float* b_ih   = (const float*)d_in[10];
    const float* b_hh   = (const float*)d_in[11];
    const float* W_fc   = (const float*)d_in[12];
    const float* b_fc   = (const float*)d_in[13];
    float* out = (float*)d_out;

    char* ws = (char*)d_ws;
    size_t o = 0;
    float* enc_proj = (float*)(ws + o);          o += (size_t)4096 * 256 * 4;
    float* gx_emb   = (float*)(ws + o);          o += (size_t)2048 * 1536 * 4;
    float* WencT    = (float*)(ws + o);          o += (size_t)256 * 512 * 4;
    float* WdecT    = (float*)(ws + o);          o += (size_t)256 * 512 * 4;
    unsigned short* Wp   = (unsigned short*)(ws + o); o += (size_t)2097152 * 2;
    unsigned short* WfcT = (unsigned short*)(ws + o); o += (size_t)32000 * 512 * 2;
    unsigned short* Hall = (unsigned short*)(ws + o); o += (size_t)2048 * 512 * 2;

    // --- prep ---
    k_trans_512x256<<<dim3(8, 16), dim3(32, 8), 0, stream>>>(W_enc, WencT);
    k_trans_512x256<<<dim3(8, 16), dim3(32, 8), 0, stream>>>(W_dec, WdecT);
    k_wfc<<<dim3(1000, 16), dim3(32, 8), 0, stream>>>(W_fc, WfcT);
    k_wpack<<<8192, 256, 0, stream>>>(W_ih, W_hh, Wp);
    k_encproj<<<256, 256, 0, stream>>>(enc, WencT, enc_proj);
    k_gxemb<<<dim3(6, 128), 256, 0, stream>>>(y, embt, W_ih, b_ih, gx_emb);

    float* attn_out = out + ATTN_OFF;

    // --- recurrence: one block per batch, no cooperative launch ---
    k_recur<<<dim3(32), dim3(512), 0, stream>>>(
        WdecT, enc_proj, v, mask, enc, attn_out, Wp, gx_emb, b_hh, dinit, Hall);

    // --- batched FC over all (b,t) ---
    k_fc<<<dim3(250, 16), 256, 0, stream>>>(Hall, WfcT, b_fc, out);
}

// Round 2
// 3094.075 us; speedup vs baseline: 2.1277x; 2.1277x over previous
//
#include <hip/hip_runtime.h>
#include <hip/hip_bf16.h>
#include <hip/hip_cooperative_groups.h>
#include <cstdint>
#include <cstddef>

namespace cg = cooperative_groups;

#define B_   32
#define T_   64
#define S_   128
#define EH   512
#define DH   512
#define ATT  256
#define EMBD 256
#define V_   32000
#define VO   31999
#define G3   1536

#define ATTN_OFF 65533952   /* 32*64*31999 */

typedef __attribute__((ext_vector_type(8))) short bf16x8;
typedef __attribute__((ext_vector_type(4))) float f32x4;

static __device__ __forceinline__ unsigned short f2bf(float f) {
    union { float f; unsigned u; } x; x.f = f;
    unsigned r = (x.u + 0x7fffu + ((x.u >> 16) & 1u)) >> 16;
    return (unsigned short)r;
}

static __device__ __forceinline__ float fast_tanh(float x) {
    float xc = fminf(fmaxf(x, -15.0f), 15.0f);
    float e = __expf(2.0f * xc);
    return (e - 1.0f) / (e + 1.0f);
}

static __device__ __forceinline__ float fast_sig(float x) {
    return 1.0f / (1.0f + __expf(-x));
}

// ---------------------------------------------------------------------------
// Prep: transpose (512,256) -> (256,512) fp32   (used for W_enc and W_dec)
__global__ void k_trans_512x256(const float* __restrict__ in, float* __restrict__ out) {
    __shared__ float tile[32][33];
    int c0 = blockIdx.x * 32;
    int r0 = blockIdx.y * 32;
    int tx = threadIdx.x, ty = threadIdx.y;
#pragma unroll
    for (int q = 0; q < 4; q++)
        tile[ty + q*8][tx] = in[(r0 + ty + q*8) * 256 + c0 + tx];
    __syncthreads();
#pragma unroll
    for (int q = 0; q < 4; q++)
        out[(c0 + ty + q*8) * 512 + r0 + tx] = tile[tx][ty + q*8];
}

// ---------------------------------------------------------------------------
// Prep: W_fc (512 x 31999) fp32 -> W_fcT (32000 x 512) bf16, pad row zeroed
__global__ void k_wfc(const float* __restrict__ wfc, unsigned short* __restrict__ outT) {
    __shared__ float tile[32][33];
    int n0 = blockIdx.x * 32;
    int k0 = blockIdx.y * 32;
    int tx = threadIdx.x, ty = threadIdx.y;
#pragma unroll
    for (int q = 0; q < 4; q++) {
        int k = k0 + ty + q*8;
        int n = n0 + tx;
        tile[ty + q*8][tx] = (n < VO) ? wfc[(size_t)k * VO + n] : 0.0f;
    }
    __syncthreads();
#pragma unroll
    for (int q = 0; q < 4; q++) {
        int n = n0 + ty + q*8;
        int k = k0 + tx;
        outT[(size_t)n * 512 + k] = f2bf(tile[tx][ty + q*8]);
    }
}

// ---------------------------------------------------------------------------
// Prep: pack GRU weights into MFMA B-fragment order, bf16.
// idx = (((j*32 + kc)*4 + q)*64 + lane)*8 + e
__global__ void k_wpack(const float* __restrict__ W_ih, const float* __restrict__ W_hh,
                        unsigned short* __restrict__ Wp) {
    int idx = blockIdx.x * 256 + threadIdx.x;
    int e    = idx & 7;
    int lane = (idx >> 3) & 63;
    int q    = (idx >> 9) & 3;
    int kc   = (idx >> 11) & 31;
    int j    = idx >> 16;
    int io = lane & 15, ko = lane >> 4;
    int i = j * 16 + io;
    int k = kc * 32 + ko * 8 + e;
    int n = (q == 0) ? i : (q == 1) ? (512 + i) : (1024 + i);
    float val;
    if (k < 512) {
        val = (q == 3) ? 0.0f : W_ih[(size_t)n * 768 + 256 + k];
    } else {
        val = (q == 2) ? 0.0f : W_hh[(size_t)n * 512 + (k - 512)];
    }
    Wp[idx] = f2bf(val);
}

// ---------------------------------------------------------------------------
// Prep: h0 = decoder_init (fp32 row-major) and X-fragment h-half of Xf0
__global__ void k_hinit2(const float* __restrict__ di, float* __restrict__ h32,
                         unsigned short* __restrict__ Xf0) {
    int idx = blockIdx.x * 256 + threadIdx.x;   // 16384
    float val = di[idx];
    h32[idx] = val;
    int b = idx >> 9, i = idx & 511;
    int mt = b >> 4, io = b & 15;
    int kc = 16 + (i >> 5), ko = (i >> 3) & 3, e = i & 7;
    Xf0[((((mt * 32 + kc) * 64) + ko * 16 + io) << 3) + e] = f2bf(val);
}

// ---------------------------------------------------------------------------
// Prep: enc_proj (4096 x 256) = encoder_outputs (4096 x 512) @ W_enc
__global__ __launch_bounds__(256) void k_encproj(const float* __restrict__ enc,
                                                 const float* __restrict__ WencT,
                                                 float* __restrict__ ep) {
    int row0 = blockIdx.x * 16;
    int n = threadIdx.x;
    const float* wr = WencT + (size_t)n * 512;
    float acc[16];
#pragma unroll
    for (int r = 0; r < 16; r++) acc[r] = 0.0f;
    for (int k = 0; k < 512; k += 4) {
        float4 w = *(const float4*)(wr + k);
#pragma unroll
        for (int r = 0; r < 16; r++) {
            float4 x = *(const float4*)(enc + (size_t)(row0 + r) * 512 + k);
            acc[r] += x.x * w.x + x.y * w.y + x.z * w.z + x.w * w.w;
        }
    }
#pragma unroll
    for (int r = 0; r < 16; r++)
        ep[(size_t)(row0 + r) * 256 + n] = acc[r];
}

// ---------------------------------------------------------------------------
// Prep: gx_emb (2048 x 1536) = embedding[y] @ W_ih[:, :256]^T + b_ih
__global__ __launch_bounds__(256) void k_gxemb(const int* __restrict__ y,
                                               const float* __restrict__ embt,
                                               const float* __restrict__ W_ih,
                                               const float* __restrict__ bih,
                                               float* __restrict__ gx) {
    int row0 = blockIdx.y * 16;
    int col = blockIdx.x * 256 + threadIdx.x;
    const float* wr = W_ih + (size_t)col * 768;
    float acc[16];
#pragma unroll
    for (int r = 0; r < 16; r++) acc[r] = 0.0f;
    for (int k = 0; k < 256; k += 4) {
        float4 w = *(const float4*)(wr + k);
#pragma unroll
        for (int r = 0; r < 16; r++) {
            const float* xr = embt + (size_t)y[row0 + r] * 256 + k;  // uniform
            float4 x = *(const float4*)xr;
            acc[r] += x.x * w.x + x.y * w.y + x.z * w.z + x.w * w.w;
        }
    }
    float bv = bih[col];
#pragma unroll
    for (int r = 0; r < 16; r++)
        gx[(size_t)(row0 + r) * G3 + col] = acc[r] + bv;
}

// ---------------------------------------------------------------------------
// Persistent cooperative kernel, 32 blocks x 512 threads.
// Block bid: attention for batch b=bid (phase A), GRU output-slice j=bid
// (48 of 1536 dims, i.e. h-dims [16j,16j+16) for each gate) for ALL batches
// (phase B). GRU weights (96 KB of B-fragments) are LDS-resident for the
// whole kernel -> zero per-step weight traffic. X=[ctx|h] is exchanged via
// global Xf buffers stored in MFMA A-fragment order (coalesced 1 KB loads).
__global__ __launch_bounds__(512) void k_recur(
        const float* __restrict__ WdecT, const float* __restrict__ ep,
        const float* __restrict__ v, const int* __restrict__ mask,
        const float* __restrict__ enc, float* __restrict__ attn_out,
        const unsigned short* __restrict__ Wp, const float* __restrict__ gx_emb,
        const float* __restrict__ b_hh, const float* __restrict__ dinit,
        unsigned short* __restrict__ Xf0, unsigned short* __restrict__ Xf1,
        float* __restrict__ h32, unsigned short* __restrict__ Hall) {
    __shared__ uint4 Wlds4[6144];      // 96 KB: q0 kc0-31 | q1 kc0-31 | q2 kc0-15 | q3 kc16-31
    __shared__ float hbuf[512];
    __shared__ float decp[512];
    __shared__ float es[128];
    __shared__ float red[2];
    __shared__ float vs[256];
    __shared__ int   msk[128];
    __shared__ float bhs[48];
    __shared__ float hloc[512];        // this block's prev-h patch: [b*16 + i2]
    __shared__ float pacc[2048];       // [ (q*2+mt)*16 + row ] * 16 + col

    cg::grid_group grid = cg::this_grid();

    int bid = blockIdx.x, tid = threadIdx.x;
    int b = bid;      // attention batch
    int j = bid;      // GRU slice
    int w = tid >> 6, lane = tid & 63;

    char* WldsB = (char*)Wlds4;

    // ---- one-time init ----
    // load this block's weight slice into LDS (96 chunks of 1 KB)
    for (int it = 0; it < 12; it++) {
        int cid = it * 512 + tid;          // 16B-chunk id, 0..6143
        int c = cid >> 6, off = cid & 63;
        int q, kc;
        if (c < 32)      { q = 0; kc = c; }
        else if (c < 64) { q = 1; kc = c - 32; }
        else if (c < 80) { q = 2; kc = c - 64; }
        else             { q = 3; kc = c - 80 + 16; }
        const uint4* src = (const uint4*)Wp + ((size_t)((j * 32 + kc) * 4 + q) << 6) + off;
        Wlds4[c * 64 + off] = *src;
    }
    if (tid < 256) vs[tid] = v[tid];
    if (tid < 128) msk[tid] = mask[b * 128 + tid];
    if (tid < 48)  bhs[tid] = b_hh[(tid >> 4) * 512 + j * 16 + (tid & 15)];
    hloc[tid] = dinit[(size_t)(tid >> 4) * 512 + j * 16 + (tid & 15)];
    __syncthreads();

    const float* epb  = ep  + (size_t)b * 128 * 256;
    const float* encb = enc + (size_t)b * 128 * 512;

    for (int t = 0; t < T_; t++) {
        unsigned short* Xcur = (t & 1) ? Xf1 : Xf0;
        unsigned short* Xnxt = (t & 1) ? Xf0 : Xf1;

        // ================= Phase A: attention for batch b =================
        hbuf[tid] = h32[b * 512 + tid];
        __syncthreads();
        // dec = h[b] @ W_dec (fp32), K split across thread halves
        {
            int d = tid & 255, half = tid >> 8;
            const float* wr = WdecT + (size_t)d * 512 + half * 256;
            const float* hb = hbuf + half * 256;
            float acc = 0.0f;
#pragma unroll 8
            for (int k = 0; k < 256; k += 4) {
                float4 wv = *(const float4*)(wr + k);
                float4 xv = *(const float4*)(hb + k);
                acc += xv.x * wv.x + xv.y * wv.y + xv.z * wv.z + xv.w * wv.w;
            }
            decp[tid] = acc;
        }
        __syncthreads();
        if (tid < 256) decp[tid] += decp[tid + 256];
        __syncthreads();
        // energy: wave w handles s = w*16 .. w*16+15
        {
            float d0 = decp[lane], d1 = decp[lane + 64],
                  d2 = decp[lane + 128], d3 = decp[lane + 192];
            float v0 = vs[lane], v1 = vs[lane + 64],
                  v2 = vs[lane + 128], v3 = vs[lane + 192];
#pragma unroll
            for (int si = 0; si < 16; si++) {
                int s = w * 16 + si;
                const float* er = epb + (size_t)s * 256;
                float e = fast_tanh(er[lane] + d0) * v0
                        + fast_tanh(er[lane + 64] + d1) * v1
                        + fast_tanh(er[lane + 128] + d2) * v2
                        + fast_tanh(er[lane + 192] + d3) * v3;
#pragma unroll
                for (int o = 32; o; o >>= 1) e += __shfl_xor(e, o);
                if (lane == 0)
                    es[s] = (msk[s] == 0) ? -1e9f : e;
            }
        }
        __syncthreads();
        // softmax over 128
        if (tid < 64) {
            float a = fmaxf(es[tid], es[tid + 64]);
#pragma unroll
            for (int o = 32; o; o >>= 1) a = fmaxf(a, __shfl_xor(a, o));
            if (tid == 0) red[0] = a;
        }
        __syncthreads();
        float mx = red[0];
        if (tid < 128) es[tid] = __expf(es[tid] - mx);
        __syncthreads();
        if (tid < 64) {
            float a = es[tid] + es[tid + 64];
#pragma unroll
            for (int o = 32; o; o >>= 1) a += __shfl_xor(a, o);
            if (tid == 0) red[1] = a;
        }
        __syncthreads();
        float inv = 1.0f / red[1];
        if (tid < 128) {
            float aw = es[tid] * inv;
            es[tid] = aw;
            attn_out[(size_t)b * (T_ * S_) + t * S_ + tid] = aw;
        }
        __syncthreads();
        // context: thread d = tid over 512 dims (fp32), write in A-frag order
        {
            float a1 = 0.0f;
            const float* eb = encb + tid;
#pragma unroll 8
            for (int s = 0; s < 128; s++)
                a1 += es[s] * eb[(size_t)s * 512];
            int d = tid;
            int hw = (((b >> 4) * 32 + (d >> 5)) * 64 + ((d >> 3) & 3) * 16 + (b & 15)) * 8 + (d & 7);
            Xcur[hw] = f2bf(a1);
        }
        grid.sync();

        // ================= Phase B: GRU slice j, all batches =================
        // prefetch gx_emb gate values for gating (independent loads)
        float ge_r, ge_z, ge_n;
        int gb = tid >> 4, gi = j * 16 + (tid & 15);
        {
            const float* g = gx_emb + (size_t)(gb * 64 + t) * G3;
            ge_r = g[gi]; ge_z = g[512 + gi]; ge_n = g[1024 + gi];
        }
        // MFMA: 6 waves: (mt = w&1, g = w>>1); g0=q0(r), g1=q1(z), g2=q2+q3(n)
        if (w < 6) {
            int mt = w & 1, g = w >> 1;
            const uint4* Xg = (const uint4*)Xcur;
            f32x4 acc0 = {0.f, 0.f, 0.f, 0.f};
            f32x4 acc1 = {0.f, 0.f, 0.f, 0.f};
            if (g < 2) {
                const char* wb = WldsB + (g ? 32768 : 0);
#pragma unroll
                for (int kc = 0; kc < 32; kc++) {
                    uint4 av = Xg[(mt * 32 + kc) * 64 + lane];
                    bf16x8 bv = *(const bf16x8*)(wb + kc * 1024 + lane * 16);
                    acc0 = __builtin_amdgcn_mfma_f32_16x16x32_bf16(*(const bf16x8*)&av, bv, acc0, 0, 0, 0);
                }
            } else {
#pragma unroll
                for (int kc = 0; kc < 16; kc++) {
                    uint4 av = Xg[(mt * 32 + kc) * 64 + lane];
                    bf16x8 bv = *(const bf16x8*)(WldsB + 65536 + kc * 1024 + lane * 16);
                    acc0 = __builtin_amdgcn_mfma_f32_16x16x32_bf16(*(const bf16x8*)&av, bv, acc0, 0, 0, 0);
                }
#pragma unroll
                for (int kc = 16; kc < 32; kc++) {
                    uint4 av = Xg[(mt * 32 + kc) * 64 + lane];
                    bf16x8 bv = *(const bf16x8*)(WldsB + 81920 + (kc - 16) * 1024 + lane * 16);
                    acc1 = __builtin_amdgcn_mfma_f32_16x16x32_bf16(*(const bf16x8*)&av, bv, acc1, 0, 0, 0);
                }
            }
            int row = lane >> 4, col = lane & 15;
            if (g < 2) {
#pragma unroll
                for (int reg = 0; reg < 4; reg++)
                    pacc[((g * 2 + mt) * 16 + row * 4 + reg) * 16 + col] = acc0[reg];
            } else {
#pragma unroll
                for (int reg = 0; reg < 4; reg++)
                    pacc[((2 * 2 + mt) * 16 + row * 4 + reg) * 16 + col] = acc0[reg];
#pragma unroll
                for (int reg = 0; reg < 4; reg++)
                    pacc[((3 * 2 + mt) * 16 + row * 4 + reg) * 16 + col] = acc1[reg];
            }
        }
        __syncthreads();
        // gating: 512 threads, (batch gb, dim i2); i = j*16+i2
        {
            int i2 = tid & 15;
            int mt = gb >> 4, rrow = gb & 15;
            float rp = pacc[((0 * 2 + mt) * 16 + rrow) * 16 + i2];
            float zp = pacc[((1 * 2 + mt) * 16 + rrow) * 16 + i2];
            float nx = pacc[((2 * 2 + mt) * 16 + rrow) * 16 + i2];
            float nh = pacc[((3 * 2 + mt) * 16 + rrow) * 16 + i2];
            float r = fast_sig(ge_r + rp + bhs[i2]);
            float z = fast_sig(ge_z + zp + bhs[16 + i2]);
            float n = fast_tanh(ge_n + nx + r * (nh + bhs[32 + i2]));
            float prev = hloc[tid];
            float hv = (1.0f - z) * n + z * prev;
            hloc[tid] = hv;
            h32[gb * 512 + gi] = hv;
            unsigned short hb16 = f2bf(hv);
            int i = gi;
            int hw = ((mt * 32 + 16 + (i >> 5)) * 64 + ((i >> 3) & 3) * 16 + rrow) * 8 + (i & 7);
            Xnxt[hw] = hb16;
            Hall[(size_t)(gb * 64 + t) * 512 + i] = hb16;
        }
        grid.sync();
    }
}

// ---------------------------------------------------------------------------
// FC: out (2048 x 31999) = H_all (2048x512) bf16 @ W_fcT^T bf16 + b_fc
// 128x128 tiles, BK=32. Epilogue stages C in LDS and writes contiguous rows.
__global__ __launch_bounds__(256) void k_fc(const unsigned short* __restrict__ A,
                                            const unsigned short* __restrict__ Bt,
                                            const float* __restrict__ bias,
                                            float* __restrict__ out) {
    __shared__ char smem[65536];
    unsigned short* Abuf = (unsigned short*)smem;            // 128*40 = 10240 B
    unsigned short* Bbuf = (unsigned short*)(smem + 10240);  // 10240 B
    int tid = threadIdx.x;
    int n0 = blockIdx.x * 128, m0 = blockIdx.y * 128;
    int w = tid >> 6, lane = tid & 63;
    int wm = w >> 1, wn = w & 1;
    int io = lane & 15, ko = lane >> 4;

    const uint4* Ag = (const uint4*)A;
    const uint4* Bg = (const uint4*)Bt;

    f32x4 z4 = {0.f, 0.f, 0.f, 0.f};
    f32x4 acc[4][4];
#pragma unroll
    for (int a = 0; a < 4; a++)
#pragma unroll
        for (int b = 0; b < 4; b++) acc[a][b] = z4;

    for (int k0 = 0; k0 < 512; k0 += 32) {
        uint4 av[2], bv[2];
#pragma unroll
        for (int u = 0; u < 2; u++) {
            int c = tid + u * 256;
            int r = c >> 2, ch = c & 3;
            av[u] = Ag[(size_t)(m0 + r) * 64 + (k0 >> 3) + ch];
            bv[u] = Bg[(size_t)(n0 + r) * 64 + (k0 >> 3) + ch];
        }
        __syncthreads();
#pragma unroll
        for (int u = 0; u < 2; u++) {
            int c = tid + u * 256;
            int r = c >> 2, ch = c & 3;
            *(uint4*)((char*)Abuf + r * 80 + ch * 16) = av[u];
            *(uint4*)((char*)Bbuf + r * 80 + ch * 16) = bv[u];
        }
        __syncthreads();
        bf16x8 af[4], bf[4];
#pragma unroll
        for (int s = 0; s < 4; s++) {
            af[s] = *(const bf16x8*)((char*)Abuf + (wm * 64 + s * 16 + io) * 80 + ko * 16);
            bf[s] = *(const bf16x8*)((char*)Bbuf + (wn * 64 + s * 16 + io) * 80 + ko * 16);
        }
#pragma unroll
        for (int sm = 0; sm < 4; sm++)
#pragma unroll
            for (int sn = 0; sn < 4; sn++)
                acc[sm][sn] = __builtin_amdgcn_mfma_f32_16x16x32_bf16(af[sm], bf[sn], acc[sm][sn], 0, 0, 0);
    }

    __syncthreads();
    float* Cst = (float*)smem;   // 128 x 128 fp32 = 64 KB
#pragma unroll
    for (int sm = 0; sm < 4; sm++)
#pragma unroll
        for (int sn = 0; sn < 4; sn++) {
            int cc = wn * 64 + sn * 16 + io;
#pragma unroll
            for (int reg = 0; reg < 4; reg++) {
                int rr = wm * 64 + sm * 16 + ko * 4 + reg;
                Cst[rr * 128 + cc] = acc[sm][sn][reg];
            }
        }
    __syncthreads();
    {
        int c = tid & 127, rh = tid >> 7;
        int ng = n0 + c;
        if (ng < VO) {
            float bv = bias[ng];
#pragma unroll 8
            for (int i = 0; i < 64; i++) {
                int r = i * 2 + rh;
                out[(size_t)(m0 + r) * VO + ng] = Cst[r * 128 + c] + bv;
            }
        }
    }
}

// ---------------------------------------------------------------------------
extern "C" void kernel_launch(void* const* d_in, const int* in_sizes, int n_in,
                              void* d_out, int out_size, void* d_ws, size_t ws_size,
                              hipStream_t stream) {
    const int*   y      = (const int*)d_in[0];
    const float* enc    = (const float*)d_in[1];
    const float* dinit  = (const float*)d_in[2];
    const int*   mask   = (const int*)d_in[3];
    const float* embt   = (const float*)d_in[4];
    const float* W_enc  = (const float*)d_in[5];
    const float* W_dec  = (const float*)d_in[6];
    const float* v      = (const float*)d_in[7];
    const float* W_ih   = (const float*)d_in[8];
    const float* W_hh   = (const float*)d_in[9];
    const float* b_ih   = (const float*)d_in[10];
    const float* b_hh   = (const float*)d_in[11];
    const float* W_fc   = (const float*)d_in[12];
    const float* b_fc   = (const float*)d_in[13];
    float* out = (float*)d_out;

    char* ws = (char*)d_ws;
    size_t o = 0;
    float* enc_proj = (float*)(ws + o);          o += (size_t)4096 * 256 * 4;
    float* gx_emb   = (float*)(ws + o);          o += (size_t)2048 * 1536 * 4;
    float* WencT    = (float*)(ws + o);          o += (size_t)256 * 512 * 4;
    float* WdecT    = (float*)(ws + o);          o += (size_t)256 * 512 * 4;
    unsigned short* Wp   = (unsigned short*)(ws + o); o += (size_t)2097152 * 2;
    unsigned short* WfcT = (unsigned short*)(ws + o); o += (size_t)32000 * 512 * 2;
    unsigned short* Hall = (unsigned short*)(ws + o); o += (size_t)2048 * 512 * 2;
    unsigned short* Xf0  = (unsigned short*)(ws + o); o += (size_t)32768 * 2;
    unsigned short* Xf1  = (unsigned short*)(ws + o); o += (size_t)32768 * 2;
    float* h32 = (float*)(ws + o);               o += (size_t)32 * 512 * 4;

    // --- prep ---
    k_trans_512x256<<<dim3(8, 16), dim3(32, 8), 0, stream>>>(W_enc, WencT);
    k_trans_512x256<<<dim3(8, 16), dim3(32, 8), 0, stream>>>(W_dec, WdecT);
    k_wfc<<<dim3(1000, 16), dim3(32, 8), 0, stream>>>(W_fc, WfcT);
    k_wpack<<<8192, 256, 0, stream>>>(W_ih, W_hh, Wp);
    k_hinit2<<<64, 256, 0, stream>>>(dinit, h32, Xf0);
    k_encproj<<<256, 256, 0, stream>>>(enc, WencT, enc_proj);
    k_gxemb<<<dim3(6, 128), 256, 0, stream>>>(y, embt, W_ih, b_ih, gx_emb);

    float* attn_out = out + ATTN_OFF;

    // --- recurrence: weight-stationary cooperative kernel, 32 blocks ---
    {
        const float* WdecT_c = WdecT; const float* ep_c = enc_proj;
        const unsigned short* Wp_c = Wp; const float* gx_c = gx_emb;
        void* args[] = {
            (void*)&WdecT_c, (void*)&ep_c, (void*)&v, (void*)&mask,
            (void*)&enc, (void*)&attn_out, (void*)&Wp_c, (void*)&gx_c,
            (void*)&b_hh, (void*)&dinit, (void*)&Xf0, (void*)&Xf1,
            (void*)&h32, (void*)&Hall
        };
        hipLaunchCooperativeKernel((void*)k_recur, dim3(32), dim3(512),
                                   args, 0, stream);
    }

    // --- batched FC over all (b,t) ---
    k_fc<<<dim3(250, 16), 256, 0, stream>>>(Hall, WfcT, b_fc, out);
}

// Round 3
// 3072.673 us; speedup vs baseline: 2.1425x; 1.0070x over previous
//
#include <hip/hip_runtime.h>
#include <hip/hip_bf16.h>
#include <hip/hip_cooperative_groups.h>
#include <cstdint>
#include <cstddef>

#define B_   32
#define T_   64
#define S_   128
#define EH   512
#define DH   512
#define ATT  256
#define EMBD 256
#define V_   32000
#define VO   31999
#define G3   1536

#define ATTN_OFF 65533952   /* 32*64*31999 */

typedef __attribute__((ext_vector_type(8))) short bf16x8;
typedef __attribute__((ext_vector_type(4))) float f32x4;

static __device__ __forceinline__ unsigned short f2bf(float f) {
    union { float f; unsigned u; } x; x.f = f;
    unsigned r = (x.u + 0x7fffu + ((x.u >> 16) & 1u)) >> 16;
    return (unsigned short)r;
}

static __device__ __forceinline__ float fast_tanh(float x) {
    float xc = fminf(fmaxf(x, -15.0f), 15.0f);
    float e = __expf(2.0f * xc);
    return (e - 1.0f) / (e + 1.0f);
}

static __device__ __forceinline__ float fast_sig(float x) {
    return 1.0f / (1.0f + __expf(-x));
}

// Load one 16-B MFMA A-fragment via two agent-scope relaxed atomic loads
// (sc1 -> reads the Infinity Cache, coherent across XCDs, no L2 invalidate).
static __device__ __forceinline__ bf16x8 ldfrag(const unsigned long long* p) {
    union { unsigned long long u[2]; bf16x8 v; } x;
    x.u[0] = __hip_atomic_load(p,     __ATOMIC_RELAXED, __HIP_MEMORY_SCOPE_AGENT);
    x.u[1] = __hip_atomic_load(p + 1, __ATOMIC_RELAXED, __HIP_MEMORY_SCOPE_AGENT);
    return x.v;
}

// Hand-rolled grid barrier: NO acquire anywhere (no buffer_inv -> L2 stays
// warm). Data crossing the barrier travels via sc1 atomics; __syncthreads()
// drains vmcnt (hipcc semantics) so all sc1 stores are IC-visible before
// tid0 arrives; arrive uses release for belt-and-suspenders ordering.
static __device__ __forceinline__ void gbar(unsigned* cnt, unsigned* gen,
                                            unsigned target) {
    __syncthreads();
    if (threadIdx.x == 0) {
        unsigned old = __hip_atomic_fetch_add(cnt, 1u, __ATOMIC_RELEASE,
                                              __HIP_MEMORY_SCOPE_AGENT);
        if (old == 31u) {
            __hip_atomic_store(cnt, 0u, __ATOMIC_RELAXED, __HIP_MEMORY_SCOPE_AGENT);
            __hip_atomic_store(gen, target, __ATOMIC_RELEASE, __HIP_MEMORY_SCOPE_AGENT);
        } else {
            while (__hip_atomic_load(gen, __ATOMIC_RELAXED,
                                     __HIP_MEMORY_SCOPE_AGENT) != target) {}
        }
    }
    __syncthreads();
}

// ---------------------------------------------------------------------------
// Prep: transpose (512,256) -> (256,512) fp32   (used for W_enc and W_dec)
__global__ void k_trans_512x256(const float* __restrict__ in, float* __restrict__ out) {
    __shared__ float tile[32][33];
    int c0 = blockIdx.x * 32;
    int r0 = blockIdx.y * 32;
    int tx = threadIdx.x, ty = threadIdx.y;
#pragma unroll
    for (int q = 0; q < 4; q++)
        tile[ty + q*8][tx] = in[(r0 + ty + q*8) * 256 + c0 + tx];
    __syncthreads();
#pragma unroll
    for (int q = 0; q < 4; q++)
        out[(c0 + ty + q*8) * 512 + r0 + tx] = tile[tx][ty + q*8];
}

// ---------------------------------------------------------------------------
// Prep: W_fc (512 x 31999) fp32 -> W_fcT (32000 x 512) bf16, pad row zeroed
__global__ void k_wfc(const float* __restrict__ wfc, unsigned short* __restrict__ outT) {
    __shared__ float tile[32][33];
    int n0 = blockIdx.x * 32;
    int k0 = blockIdx.y * 32;
    int tx = threadIdx.x, ty = threadIdx.y;
#pragma unroll
    for (int q = 0; q < 4; q++) {
        int k = k0 + ty + q*8;
        int n = n0 + tx;
        tile[ty + q*8][tx] = (n < VO) ? wfc[(size_t)k * VO + n] : 0.0f;
    }
    __syncthreads();
#pragma unroll
    for (int q = 0; q < 4; q++) {
        int n = n0 + ty + q*8;
        int k = k0 + tx;
        outT[(size_t)n * 512 + k] = f2bf(tile[tx][ty + q*8]);
    }
}

// ---------------------------------------------------------------------------
// Prep: pack GRU weights into MFMA B-fragment order, bf16.
// idx = (((j*32 + kc)*4 + q)*64 + lane)*8 + e
__global__ void k_wpack(const float* __restrict__ W_ih, const float* __restrict__ W_hh,
                        unsigned short* __restrict__ Wp) {
    int idx = blockIdx.x * 256 + threadIdx.x;
    int e    = idx & 7;
    int lane = (idx >> 3) & 63;
    int q    = (idx >> 9) & 3;
    int kc   = (idx >> 11) & 31;
    int j    = idx >> 16;
    int io = lane & 15, ko = lane >> 4;
    int i = j * 16 + io;
    int k = kc * 32 + ko * 8 + e;
    int n = (q == 0) ? i : (q == 1) ? (512 + i) : (1024 + i);
    float val;
    if (k < 512) {
        val = (q == 3) ? 0.0f : W_ih[(size_t)n * 768 + 256 + k];
    } else {
        val = (q == 2) ? 0.0f : W_hh[(size_t)n * 512 + (k - 512)];
    }
    Wp[idx] = f2bf(val);
}

// ---------------------------------------------------------------------------
// Prep: h0 = decoder_init (fp32 row-major) and X-fragment h-half of Xf0;
// also zeroes the grid-barrier state (graph-capture safe: runs every launch).
__global__ void k_hinit2(const float* __restrict__ di, float* __restrict__ h32,
                         unsigned short* __restrict__ Xf0, unsigned* __restrict__ bar) {
    int idx = blockIdx.x * 256 + threadIdx.x;   // 16384
    float val = di[idx];
    h32[idx] = val;
    int b = idx >> 9, i = idx & 511;
    int mt = b >> 4, io = b & 15;
    int kc = 16 + (i >> 5), ko = (i >> 3) & 3, e = i & 7;
    Xf0[((((mt * 32 + kc) * 64) + ko * 16 + io) << 3) + e] = f2bf(val);
    if (idx == 0) { bar[0] = 0u; bar[1] = 0u; }
}

// ---------------------------------------------------------------------------
// Prep: enc_proj (4096 x 256) = encoder_outputs (4096 x 512) @ W_enc
__global__ __launch_bounds__(256) void k_encproj(const float* __restrict__ enc,
                                                 const float* __restrict__ WencT,
                                                 float* __restrict__ ep) {
    int row0 = blockIdx.x * 16;
    int n = threadIdx.x;
    const float* wr = WencT + (size_t)n * 512;
    float acc[16];
#pragma unroll
    for (int r = 0; r < 16; r++) acc[r] = 0.0f;
    for (int k = 0; k < 512; k += 4) {
        float4 w = *(const float4*)(wr + k);
#pragma unroll
        for (int r = 0; r < 16; r++) {
            float4 x = *(const float4*)(enc + (size_t)(row0 + r) * 512 + k);
            acc[r] += x.x * w.x + x.y * w.y + x.z * w.z + x.w * w.w;
        }
    }
#pragma unroll
    for (int r = 0; r < 16; r++)
        ep[(size_t)(row0 + r) * 256 + n] = acc[r];
}

// ---------------------------------------------------------------------------
// Prep: gx_emb (2048 x 1536) = embedding[y] @ W_ih[:, :256]^T + b_ih
__global__ __launch_bounds__(256) void k_gxemb(const int* __restrict__ y,
                                               const float* __restrict__ embt,
                                               const float* __restrict__ W_ih,
                                               const float* __restrict__ bih,
                                               float* __restrict__ gx) {
    int row0 = blockIdx.y * 16;
    int col = blockIdx.x * 256 + threadIdx.x;
    const float* wr = W_ih + (size_t)col * 768;
    float acc[16];
#pragma unroll
    for (int r = 0; r < 16; r++) acc[r] = 0.0f;
    for (int k = 0; k < 256; k += 4) {
        float4 w = *(const float4*)(wr + k);
#pragma unroll
        for (int r = 0; r < 16; r++) {
            const float* xr = embt + (size_t)y[row0 + r] * 256 + k;  // uniform
            float4 x = *(const float4*)xr;
            acc[r] += x.x * w.x + x.y * w.y + x.z * w.z + x.w * w.w;
        }
    }
    float bv = bih[col];
#pragma unroll
    for (int r = 0; r < 16; r++)
        gx[(size_t)(row0 + r) * G3 + col] = acc[r] + bv;
}

// ---------------------------------------------------------------------------
// Persistent cooperative kernel, 32 blocks x 512 threads.
// Block bid: attention for batch b=bid (phase A), GRU output-slice j=bid
// for ALL batches (phase B). GRU weights LDS-resident. Cross-block data
// (Xf, h32) moves via agent-scope relaxed sc1 atomics; grid barrier is
// hand-rolled (no L2 invalidation -> read-only data stays L2-resident).
__global__ __launch_bounds__(512) void k_recur(
        const float* __restrict__ WdecT, const float* __restrict__ ep,
        const float* __restrict__ v, const int* __restrict__ mask,
        const float* __restrict__ enc, float* __restrict__ attn_out,
        const unsigned short* __restrict__ Wp, const float* __restrict__ gx_emb,
        const float* __restrict__ b_hh, const float* __restrict__ dinit,
        unsigned short* __restrict__ Xf0, unsigned short* __restrict__ Xf1,
        float* __restrict__ h32, unsigned short* __restrict__ Hall,
        unsigned* __restrict__ bar) {
    __shared__ uint4 Wlds4[6144];      // 96 KB: q0 kc0-31 | q1 kc0-31 | q2 kc0-15 | q3 kc16-31
    __shared__ float hbuf[512];
    __shared__ float decp[512];
    __shared__ float es[128];
    __shared__ float red[2];
    __shared__ float vs[256];
    __shared__ int   msk[128];
    __shared__ float bhs[48];
    __shared__ float hloc[512];        // this block's prev-h patch: [b*16 + i2]
    __shared__ float pacc[2048];       // [ (q*2+mt)*16 + row ] * 16 + col
    __shared__ unsigned g0s;

    int bid = blockIdx.x, tid = threadIdx.x;
    int b = bid;      // attention batch
    int j = bid;      // GRU slice
    int w = tid >> 6, lane = tid & 63;

    char* WldsB = (char*)Wlds4;
    unsigned* bcnt = bar;
    unsigned* bgen = bar + 1;

    // ---- one-time init ----
    for (int it = 0; it < 12; it++) {
        int cid = it * 512 + tid;          // 16B-chunk id, 0..6143
        int c = cid >> 6, off = cid & 63;
        int q, kc;
        if (c < 32)      { q = 0; kc = c; }
        else if (c < 64) { q = 1; kc = c - 32; }
        else if (c < 80) { q = 2; kc = c - 64; }
        else             { q = 3; kc = c - 80 + 16; }
        const uint4* src = (const uint4*)Wp + ((size_t)((j * 32 + kc) * 4 + q) << 6) + off;
        Wlds4[c * 64 + off] = *src;
    }
    if (tid < 256) vs[tid] = v[tid];
    if (tid < 128) msk[tid] = mask[b * 128 + tid];
    if (tid < 48)  bhs[tid] = b_hh[(tid >> 4) * 512 + j * 16 + (tid & 15)];
    hloc[tid] = dinit[(size_t)(tid >> 4) * 512 + j * 16 + (tid & 15)];
    if (tid == 0)
        g0s = __hip_atomic_load(bgen, __ATOMIC_RELAXED, __HIP_MEMORY_SCOPE_AGENT);
    __syncthreads();
    unsigned bt = g0s;

    const float* epb  = ep  + (size_t)b * 128 * 256;
    const float* encb = enc + (size_t)b * 128 * 512;

    for (int t = 0; t < T_; t++) {
        unsigned short* Xcur = (t & 1) ? Xf1 : Xf0;
        unsigned short* Xnxt = (t & 1) ? Xf0 : Xf1;

        // ================= Phase A: attention for batch b =================
        hbuf[tid] = __hip_atomic_load(&h32[b * 512 + tid], __ATOMIC_RELAXED,
                                      __HIP_MEMORY_SCOPE_AGENT);
        __syncthreads();
        // dec = h[b] @ W_dec (fp32), K split across thread halves
        {
            int d = tid & 255, half = tid >> 8;
            const float* wr = WdecT + (size_t)d * 512 + half * 256;
            const float* hb = hbuf + half * 256;
            float acc = 0.0f;
#pragma unroll 8
            for (int k = 0; k < 256; k += 4) {
                float4 wv = *(const float4*)(wr + k);
                float4 xv = *(const float4*)(hb + k);
                acc += xv.x * wv.x + xv.y * wv.y + xv.z * wv.z + xv.w * wv.w;
            }
            decp[tid] = acc;
        }
        __syncthreads();
        if (tid < 256) decp[tid] += decp[tid + 256];
        __syncthreads();
        // energy: wave w handles s = w*16 .. w*16+15
        {
            float d0 = decp[lane], d1 = decp[lane + 64],
                  d2 = decp[lane + 128], d3 = decp[lane + 192];
            float v0 = vs[lane], v1 = vs[lane + 64],
                  v2 = vs[lane + 128], v3 = vs[lane + 192];
#pragma unroll
            for (int si = 0; si < 16; si++) {
                int s = w * 16 + si;
                const float* er = epb + (size_t)s * 256;
                float e = fast_tanh(er[lane] + d0) * v0
                        + fast_tanh(er[lane + 64] + d1) * v1
                        + fast_tanh(er[lane + 128] + d2) * v2
                        + fast_tanh(er[lane + 192] + d3) * v3;
#pragma unroll
                for (int o = 32; o; o >>= 1) e += __shfl_xor(e, o);
                if (lane == 0)
                    es[s] = (msk[s] == 0) ? -1e9f : e;
            }
        }
        __syncthreads();
        // softmax over 128
        if (tid < 64) {
            float a = fmaxf(es[tid], es[tid + 64]);
#pragma unroll
            for (int o = 32; o; o >>= 1) a = fmaxf(a, __shfl_xor(a, o));
            if (tid == 0) red[0] = a;
        }
        __syncthreads();
        float mx = red[0];
        if (tid < 128) es[tid] = __expf(es[tid] - mx);
        __syncthreads();
        if (tid < 64) {
            float a = es[tid] + es[tid + 64];
#pragma unroll
            for (int o = 32; o; o >>= 1) a += __shfl_xor(a, o);
            if (tid == 0) red[1] = a;
        }
        __syncthreads();
        float inv = 1.0f / red[1];
        if (tid < 128) {
            float aw = es[tid] * inv;
            es[tid] = aw;
            attn_out[(size_t)b * (T_ * S_) + t * S_ + tid] = aw;
        }
        __syncthreads();
        // context: thread d = tid over 512 dims (fp32); pack pairs into
        // uint and store via agent-relaxed atomics (sc1 write-through).
        {
            float a1 = 0.0f;
            const float* eb = encb + tid;
#pragma unroll 8
            for (int s = 0; s < 128; s++)
                a1 += es[s] * eb[(size_t)s * 512];
            int d = tid;
            unsigned short mybf = f2bf(a1);
            int oth = __shfl_down((int)mybf, 1);
            int hw = (((b >> 4) * 32 + (d >> 5)) * 64 + ((d >> 3) & 3) * 16 + (b & 15)) * 8 + (d & 7);
            if (!(d & 1)) {
                unsigned pk = ((unsigned)mybf & 0xffffu) | ((unsigned)oth << 16);
                __hip_atomic_store((unsigned*)Xcur + (hw >> 1), pk,
                                   __ATOMIC_RELAXED, __HIP_MEMORY_SCOPE_AGENT);
            }
        }
        gbar(bcnt, bgen, ++bt);

        // ================= Phase B: GRU slice j, all batches =================
        float ge_r, ge_z, ge_n;
        int gb = tid >> 4, gi = j * 16 + (tid & 15);
        {
            const float* g = gx_emb + (size_t)(gb * 64 + t) * G3;
            ge_r = g[gi]; ge_z = g[512 + gi]; ge_n = g[1024 + gi];
        }
        // MFMA: 6 waves: (mt = w&1, g = w>>1); g0=q0(r), g1=q1(z), g2=q2+q3(n)
        if (w < 6) {
            int mt = w & 1, g = w >> 1;
            const unsigned long long* Xg8 = (const unsigned long long*)Xcur;
            f32x4 acc0 = {0.f, 0.f, 0.f, 0.f};
            f32x4 acc1 = {0.f, 0.f, 0.f, 0.f};
            if (g < 2) {
                const char* wb = WldsB + (g ? 32768 : 0);
#pragma unroll
                for (int kc = 0; kc < 32; kc++) {
                    bf16x8 av = ldfrag(Xg8 + (size_t)((mt * 32 + kc) * 64 + lane) * 2);
                    bf16x8 bv = *(const bf16x8*)(wb + kc * 1024 + lane * 16);
                    acc0 = __builtin_amdgcn_mfma_f32_16x16x32_bf16(av, bv, acc0, 0, 0, 0);
                }
            } else {
#pragma unroll
                for (int kc = 0; kc < 16; kc++) {
                    bf16x8 av = ldfrag(Xg8 + (size_t)((mt * 32 + kc) * 64 + lane) * 2);
                    bf16x8 bv = *(const bf16x8*)(WldsB + 65536 + kc * 1024 + lane * 16);
                    acc0 = __builtin_amdgcn_mfma_f32_16x16x32_bf16(av, bv, acc0, 0, 0, 0);
                }
#pragma unroll
                for (int kc = 16; kc < 32; kc++) {
                    bf16x8 av = ldfrag(Xg8 + (size_t)((mt * 32 + kc) * 64 + lane) * 2);
                    bf16x8 bv = *(const bf16x8*)(WldsB + 81920 + (kc - 16) * 1024 + lane * 16);
                    acc1 = __builtin_amdgcn_mfma_f32_16x16x32_bf16(av, bv, acc1, 0, 0, 0);
                }
            }
            int row = lane >> 4, col = lane & 15;
            if (g < 2) {
#pragma unroll
                for (int reg = 0; reg < 4; reg++)
                    pacc[((g * 2 + mt) * 16 + row * 4 + reg) * 16 + col] = acc0[reg];
            } else {
#pragma unroll
                for (int reg = 0; reg < 4; reg++)
                    pacc[((2 * 2 + mt) * 16 + row * 4 + reg) * 16 + col] = acc0[reg];
#pragma unroll
                for (int reg = 0; reg < 4; reg++)
                    pacc[((3 * 2 + mt) * 16 + row * 4 + reg) * 16 + col] = acc1[reg];
            }
        }
        __syncthreads();
        // gating: 512 threads, (batch gb, dim i2); i = j*16+i2
        {
            int i2 = tid & 15;
            int mt = gb >> 4, rrow = gb & 15;
            float rp = pacc[((0 * 2 + mt) * 16 + rrow) * 16 + i2];
            float zp = pacc[((1 * 2 + mt) * 16 + rrow) * 16 + i2];
            float nx = pacc[((2 * 2 + mt) * 16 + rrow) * 16 + i2];
            float nh = pacc[((3 * 2 + mt) * 16 + rrow) * 16 + i2];
            float r = fast_sig(ge_r + rp + bhs[i2]);
            float z = fast_sig(ge_z + zp + bhs[16 + i2]);
            float n = fast_tanh(ge_n + nx + r * (nh + bhs[32 + i2]));
            float prev = hloc[tid];
            float hv = (1.0f - z) * n + z * prev;
            hloc[tid] = hv;
            __hip_atomic_store(&h32[gb * 512 + gi], hv, __ATOMIC_RELAXED,
                               __HIP_MEMORY_SCOPE_AGENT);
            unsigned short hb16 = f2bf(hv);
            int oth = __shfl_down((int)hb16, 1);
            int i = gi;
            int hw = ((mt * 32 + 16 + (i >> 5)) * 64 + ((i >> 3) & 3) * 16 + rrow) * 8 + (i & 7);
            if (!(tid & 1)) {
                unsigned pk = ((unsigned)hb16 & 0xffffu) | ((unsigned)oth << 16);
                __hip_atomic_store((unsigned*)Xnxt + (hw >> 1), pk,
                                   __ATOMIC_RELAXED, __HIP_MEMORY_SCOPE_AGENT);
            }
            Hall[(size_t)(gb * 64 + t) * 512 + i] = hb16;
        }
        gbar(bcnt, bgen, ++bt);
    }
}

// ---------------------------------------------------------------------------
// FC: out (2048 x 31999) = H_all (2048x512) bf16 @ W_fcT^T bf16 + b_fc
// 128x128 tiles, BK=32. Epilogue stages C in LDS and writes contiguous rows.
__global__ __launch_bounds__(256) void k_fc(const unsigned short* __restrict__ A,
                                            const unsigned short* __restrict__ Bt,
                                            const float* __restrict__ bias,
                                            float* __restrict__ out) {
    __shared__ char smem[65536];
    unsigned short* Abuf = (unsigned short*)smem;            // 128*40 = 10240 B
    unsigned short* Bbuf = (unsigned short*)(smem + 10240);  // 10240 B
    int tid = threadIdx.x;
    int n0 = blockIdx.x * 128, m0 = blockIdx.y * 128;
    int w = tid >> 6, lane = tid & 63;
    int wm = w >> 1, wn = w & 1;
    int io = lane & 15, ko = lane >> 4;

    const uint4* Ag = (const uint4*)A;
    const uint4* Bg = (const uint4*)Bt;

    f32x4 z4 = {0.f, 0.f, 0.f, 0.f};
    f32x4 acc[4][4];
#pragma unroll
    for (int a = 0; a < 4; a++)
#pragma unroll
        for (int b = 0; b < 4; b++) acc[a][b] = z4;

    for (int k0 = 0; k0 < 512; k0 += 32) {
        uint4 av[2], bv[2];
#pragma unroll
        for (int u = 0; u < 2; u++) {
            int c = tid + u * 256;
            int r = c >> 2, ch = c & 3;
            av[u] = Ag[(size_t)(m0 + r) * 64 + (k0 >> 3) + ch];
            bv[u] = Bg[(size_t)(n0 + r) * 64 + (k0 >> 3) + ch];
        }
        __syncthreads();
#pragma unroll
        for (int u = 0; u < 2; u++) {
            int c = tid + u * 256;
            int r = c >> 2, ch = c & 3;
            *(uint4*)((char*)Abuf + r * 80 + ch * 16) = av[u];
            *(uint4*)((char*)Bbuf + r * 80 + ch * 16) = bv[u];
        }
        __syncthreads();
        bf16x8 af[4], bf[4];
#pragma unroll
        for (int s = 0; s < 4; s++) {
            af[s] = *(const bf16x8*)((char*)Abuf + (wm * 64 + s * 16 + io) * 80 + ko * 16);
            bf[s] = *(const bf16x8*)((char*)Bbuf + (wn * 64 + s * 16 + io) * 80 + ko * 16);
        }
#pragma unroll
        for (int sm = 0; sm < 4; sm++)
#pragma unroll
            for (int sn = 0; sn < 4; sn++)
                acc[sm][sn] = __builtin_amdgcn_mfma_f32_16x16x32_bf16(af[sm], bf[sn], acc[sm][sn], 0, 0, 0);
    }

    __syncthreads();
    float* Cst = (float*)smem;   // 128 x 128 fp32 = 64 KB
#pragma unroll
    for (int sm = 0; sm < 4; sm++)
#pragma unroll
        for (int sn = 0; sn < 4; sn++) {
            int cc = wn * 64 + sn * 16 + io;
#pragma unroll
            for (int reg = 0; reg < 4; reg++) {
                int rr = wm * 64 + sm * 16 + ko * 4 + reg;
                Cst[rr * 128 + cc] = acc[sm][sn][reg];
            }
        }
    __syncthreads();
    {
        int c = tid & 127, rh = tid >> 7;
        int ng = n0 + c;
        if (ng < VO) {
            float bv = bias[ng];
#pragma unroll 8
            for (int i = 0; i < 64; i++) {
                int r = i * 2 + rh;
                out[(size_t)(m0 + r) * VO + ng] = Cst[r * 128 + c] + bv;
            }
        }
    }
}

// ---------------------------------------------------------------------------
extern "C" void kernel_launch(void* const* d_in, const int* in_sizes, int n_in,
                              void* d_out, int out_size, void* d_ws, size_t ws_size,
                              hipStream_t stream) {
    const int*   y      = (const int*)d_in[0];
    const float* enc    = (const float*)d_in[1];
    const float* dinit  = (const float*)d_in[2];
    const int*   mask   = (const int*)d_in[3];
    const float* embt   = (const float*)d_in[4];
    const float* W_enc  = (const float*)d_in[5];
    const float* W_dec  = (const float*)d_in[6];
    const float* v      = (const float*)d_in[7];
    const float* W_ih   = (const float*)d_in[8];
    const float* W_hh   = (const float*)d_in[9];
    const float* b_ih   = (const float*)d_in[10];
    const float* b_hh   = (const float*)d_in[11];
    const float* W_fc   = (const float*)d_in[12];
    const float* b_fc   = (const float*)d_in[13];
    float* out = (float*)d_out;

    char* ws = (char*)d_ws;
    size_t o = 0;
    float* enc_proj = (float*)(ws + o);          o += (size_t)4096 * 256 * 4;
    float* gx_emb   = (float*)(ws + o);          o += (size_t)2048 * 1536 * 4;
    float* WencT    = (float*)(ws + o);          o += (size_t)256 * 512 * 4;
    float* WdecT    = (float*)(ws + o);          o += (size_t)256 * 512 * 4;
    unsigned short* Wp   = (unsigned short*)(ws + o); o += (size_t)2097152 * 2;
    unsigned short* WfcT = (unsigned short*)(ws + o); o += (size_t)32000 * 512 * 2;
    unsigned short* Hall = (unsigned short*)(ws + o); o += (size_t)2048 * 512 * 2;
    unsigned short* Xf0  = (unsigned short*)(ws + o); o += (size_t)32768 * 2;
    unsigned short* Xf1  = (unsigned short*)(ws + o); o += (size_t)32768 * 2;
    float* h32 = (float*)(ws + o);               o += (size_t)32 * 512 * 4;
    unsigned* bar = (unsigned*)(ws + o);         o += 256;

    // --- prep ---
    k_trans_512x256<<<dim3(8, 16), dim3(32, 8), 0, stream>>>(W_enc, WencT);
    k_trans_512x256<<<dim3(8, 16), dim3(32, 8), 0, stream>>>(W_dec, WdecT);
    k_wfc<<<dim3(1000, 16), dim3(32, 8), 0, stream>>>(W_fc, WfcT);
    k_wpack<<<8192, 256, 0, stream>>>(W_ih, W_hh, Wp);
    k_hinit2<<<64, 256, 0, stream>>>(dinit, h32, Xf0, bar);
    k_encproj<<<256, 256, 0, stream>>>(enc, WencT, enc_proj);
    k_gxemb<<<dim3(6, 128), 256, 0, stream>>>(y, embt, W_ih, b_ih, gx_emb);

    float* attn_out = out + ATTN_OFF;

    // --- recurrence: weight-stationary cooperative kernel, 32 blocks ---
    {
        const float* WdecT_c = WdecT; const float* ep_c = enc_proj;
        const unsigned short* Wp_c = Wp; const float* gx_c = gx_emb;
        void* args[] = {
            (void*)&WdecT_c, (void*)&ep_c, (void*)&v, (void*)&mask,
            (void*)&enc, (void*)&attn_out, (void*)&Wp_c, (void*)&gx_c,
            (void*)&b_hh, (void*)&dinit, (void*)&Xf0, (void*)&Xf1,
            (void*)&h32, (void*)&Hall, (void*)&bar
        };
        hipLaunchCooperativeKernel((void*)k_recur, dim3(32), dim3(512),
                                   args, 0, stream);
    }

    // --- batched FC over all (b,t) ---
    k_fc<<<dim3(250, 16), 256, 0, stream>>>(Hall, WfcT, b_fc, out);
}